// Round 5
// baseline (157.396 us; speedup 1.0000x reference)
//
#include <hip/hip_runtime.h>
#include <stdint.h>

// B=32, La=512, Lq=64, H=1024. Score path split-bf16 (3 MFMA), value path bf16.
// All GEMMs: LDS double-buffered, stage(k+1) issued BEFORE compute(k), one barrier/K-step.
// g1: Pcat = Q(split)@Wcat^T (remap) || P3T = (Q@W21)^T
// g2: scores = A(split, fp32 reg-staged)@Pcat^T, tile 64x128; fused aq row-softmax;
//     qa half written fp32 to Spack2
// softmax_cols: qa = colsoftmax(Spack2) bf16
// g3: PmaxA = colmax(relu(aq@P3T^T)) || ctx = qa@A (A fp32 reg-staged, k-major)
// g4: PmaxQ = colmax64(relu(ctx@W22T^T))
// final: out = 0.5*max4(PmaxA) + 0.5*PmaxQ

using bf16x8 = __attribute__((ext_vector_type(8))) short;
using f32x4  = __attribute__((ext_vector_type(4))) float;
typedef const __attribute__((address_space(1))) void* gas_t;
typedef __attribute__((address_space(3))) void* las_t;

__device__ __forceinline__ unsigned short f2bf(float x) {
  unsigned u = __builtin_bit_cast(unsigned, x);
  u += 0x7fffu + ((u >> 16) & 1u);
  return (unsigned short)(u >> 16);
}
__device__ __forceinline__ float bf2f(unsigned short h) {
  unsigned u = ((unsigned)h) << 16;
  return __builtin_bit_cast(float, u);
}

// ---------------- prep ----------------

__global__ __launch_bounds__(256) void conv_split(const float* __restrict__ in,
    unsigned short* __restrict__ hi, unsigned short* __restrict__ lo, int n4)
{
  int i = blockIdx.x * 256 + threadIdx.x;
  if (i >= n4) return;
  float4 v = ((const float4*)in)[i];
  ushort4 h, l;
  h.x = f2bf(v.x); l.x = f2bf(v.x - bf2f(h.x));
  h.y = f2bf(v.y); l.y = f2bf(v.y - bf2f(h.y));
  h.z = f2bf(v.z); l.z = f2bf(v.z - bf2f(h.z));
  h.w = f2bf(v.w); l.w = f2bf(v.w - bf2f(h.w));
  ((ushort4*)hi)[i] = h;
  ((ushort4*)lo)[i] = l;
}

// z=0: W11 split straight; z=1: W12 transpose-split; z=2: W21T; z=3: W22T
__global__ __launch_bounds__(256) void prep_W(
    const float* __restrict__ W11, const float* __restrict__ W12,
    const float* __restrict__ W21, const float* __restrict__ W22,
    unsigned short* __restrict__ Wcat_hi, unsigned short* __restrict__ Wcat_lo,
    unsigned short* __restrict__ W21T, unsigned short* __restrict__ W22T)
{
  __shared__ float tile[32][33];
  int z = blockIdx.z;
  const float* src = z == 0 ? W11 : z == 1 ? W12 : z == 2 ? W21 : W22;
  int r0 = blockIdx.y * 32, c0 = blockIdx.x * 32;
  int tx = threadIdx.x, ty = threadIdx.y;
  #pragma unroll
  for (int i = 0; i < 4; ++i) {
    int r = r0 + ty + i * 8;
    float v = src[(long)r * 1024 + c0 + tx];
    tile[ty + i * 8][tx] = v;
    if (z == 0) {
      long o = (long)r * 1024 + c0 + tx;
      unsigned short h = f2bf(v);
      Wcat_hi[o] = h;
      Wcat_lo[o] = f2bf(v - bf2f(h));
    }
  }
  __syncthreads();
  if (z > 0) {
    #pragma unroll
    for (int i = 0; i < 4; ++i) {
      float v = tile[tx][ty + i * 8];
      long o = (long)(c0 + ty + i * 8) * 1024 + r0 + tx;
      unsigned short h = f2bf(v);
      if (z == 1) {
        Wcat_hi[1048576 + o] = h;
        Wcat_lo[1048576 + o] = f2bf(v - bf2f(h));
      } else if (z == 2) W21T[o] = h;
      else W22T[o] = h;
    }
  }
}

// ---------------- generic MFMA GEMM body (C = A @ B^T), double-buffered ----------------
// OUT: 1=Pcat split remap, 2=bf16 (row<M), 3=P3T transpose, 4=relu+colmax(BM),
// 5=relu+colmax per 64 rows. BF32: B operand fp32 [K x ldB] (k-major), reg-staged.
template<int BM, int BN, bool SPLIT, int OUT, bool BF32>
__device__ __forceinline__ void gemm_body(
    char* smem, int bx, int by, int z,
    const unsigned short* __restrict__ Ah, const unsigned short* __restrict__ Al,
    const unsigned short* __restrict__ Bh, const unsigned short* __restrict__ Bl,
    const float* __restrict__ Bf,
    float* __restrict__ Cf, unsigned short* __restrict__ Ch, unsigned short* __restrict__ Cl,
    int M, int N, int K, int ldA, int ldB, int ldC, long sA, long sB, long sC, int mtiles)
{
  constexpr int AB = BM * 64, BB = BN * 64;
  constexpr int ASZ = SPLIT ? 2 * AB : AB;
  constexpr int HALF = ASZ + (SPLIT ? 2 * BB : BB);
  constexpr int MI = BM / 32, NI = BN / 32;

  const int m0 = by * BM, n0 = bx * BN;
  const int t = threadIdx.x, lane = t & 63;
  const int wid = t >> 6, wr = wid >> 1, wc = wid & 1;

  const unsigned short* Ab  = Ah + (long)z * sA;
  const unsigned short* Bb  = BF32 ? nullptr : Bh + (long)z * sB;
  const unsigned short* Abl = SPLIT ? Al + (long)z * sA : nullptr;
  const unsigned short* Bbl = SPLIT ? Bl + (long)z * sB : nullptr;
  const float* Bfb = BF32 ? Bf + (long)z * sB : nullptr;

  auto As  = [&](int c) { return smem + c * HALF; };
  auto Asl = [&](int c) { return smem + c * HALF + AB; };
  auto Bsp = [&](int c) { return smem + c * HALF + ASZ; };
  auto Bsl = [&](int c) { return smem + c * HALF + ASZ + BB; };

  f32x4 acc[MI][NI];
  #pragma unroll
  for (int i = 0; i < MI; ++i)
    #pragma unroll
    for (int j = 0; j < NI; ++j)
      acc[i][j] = f32x4{0.f, 0.f, 0.f, 0.f};

  auto stage4k = [&](char* lbuf, const unsigned short* g, int ld, int row0, int k0, int rmax) {
    int ob = t * 16;
    int e  = ob ^ (((ob >> 7) & 3) << 4);
    int m  = e >> 6, k = (e & 63) >> 1;
    int row = row0 + m; row = row < rmax ? row : rmax - 1;
    const unsigned short* gp = g + (long)row * ld + k0 + k;
    char* lp = lbuf + (t & ~63) * 16;  // wave-uniform; HW adds lane*16
    __builtin_amdgcn_global_load_lds((gas_t)(const void*)gp, (las_t)(void*)lp, 16, 0, 0);
  };

  float bv[8];  // BF32 reg-staged B (global->reg issued early; cvt+write late)
  auto loadB8 = [&](int k0) {
    int ob = t * 16;
    int e  = ob ^ (((ob >> 7) & 3) << 4);
    int n  = e >> 6, kb = (e & 63) >> 1;
    #pragma unroll
    for (int j = 0; j < 8; ++j)
      bv[j] = Bfb[(long)(k0 + kb + j) * ldB + n0 + n];
  };
  auto writeB8 = [&](char* lbuf) {
    int ob = t * 16;
    bf16x8 pk;
    #pragma unroll
    for (int j = 0; j < 8; ++j) pk[j] = (short)f2bf(bv[j]);
    *(bf16x8*)(lbuf + ob) = pk;
  };

  auto stageAsync = [&](int c, int k0) {
    stage4k(As(c), Ab, ldA, m0, k0, M);
    if (BM == 128) stage4k(As(c) + 4096, Ab, ldA, m0 + 64, k0, M);
    if (!BF32) {
      stage4k(Bsp(c), Bb, ldB, n0, k0, N);
      if (BN == 128) stage4k(Bsp(c) + 4096, Bb, ldB, n0 + 64, k0, N);
    }
    if (SPLIT) {
      stage4k(Asl(c), Abl, ldA, m0, k0, M);
      if (BM == 128) stage4k(Asl(c) + 4096, Abl, ldA, m0 + 64, k0, M);
      stage4k(Bsl(c), Bbl, ldB, n0, k0, N);
      if (BN == 128) stage4k(Bsl(c) + 4096, Bbl, ldB, n0 + 64, k0, N);
    }
  };

  auto ldfrag = [&](const char* lbuf, int rr) -> bf16x8 {
    int ob = rr * 64 + (lane >> 4) * 16;
    ob ^= ((ob >> 7) & 3) << 4;
    return *(const bf16x8*)(lbuf + ob);
  };

  // prologue
  if (BF32) loadB8(0);
  stageAsync(0, 0);
  if (BF32) writeB8(Bsp(0));
  __syncthreads();

  int cur = 0;
  for (int k0 = 0; k0 < K; k0 += 32) {
    bool more = (k0 + 32) < K;
    if (BF32 && more) loadB8(k0 + 32);
    if (more) stageAsync(cur ^ 1, k0 + 32);

    bf16x8 ah[MI], al[MI];
    #pragma unroll
    for (int mi = 0; mi < MI; ++mi) {
      int rr = wr * (BM / 2) + mi * 16 + (lane & 15);
      ah[mi] = ldfrag(As(cur), rr);
      if (SPLIT) al[mi] = ldfrag(Asl(cur), rr);
    }
    #pragma unroll
    for (int ni = 0; ni < NI; ++ni) {
      int rc = wc * (BN / 2) + ni * 16 + (lane & 15);
      bf16x8 bh = ldfrag(Bsp(cur), rc);
      bf16x8 bl;
      if (SPLIT) bl = ldfrag(Bsl(cur), rc);
      #pragma unroll
      for (int mi = 0; mi < MI; ++mi) {
        acc[mi][ni] = __builtin_amdgcn_mfma_f32_16x16x32_bf16(ah[mi], bh, acc[mi][ni], 0, 0, 0);
        if (SPLIT) {
          acc[mi][ni] = __builtin_amdgcn_mfma_f32_16x16x32_bf16(ah[mi], bl, acc[mi][ni], 0, 0, 0);
          acc[mi][ni] = __builtin_amdgcn_mfma_f32_16x16x32_bf16(al[mi], bh, acc[mi][ni], 0, 0, 0);
        }
      }
    }
    if (BF32 && more) writeB8(Bsp(cur ^ 1));
    __syncthreads();
    cur ^= 1;
  }

  if (OUT == 4 || OUT == 5) {
    float* red = (float*)smem;  // safe: loop ended with __syncthreads
    #pragma unroll
    for (int ni = 0; ni < NI; ++ni) {
      float pm = 0.0f;  // relu floor
      #pragma unroll
      for (int mi = 0; mi < MI; ++mi)
        #pragma unroll
        for (int r = 0; r < 4; ++r)
          pm = fmaxf(pm, acc[mi][ni][r]);
      int g = wr * 4 + (lane >> 4);
      int col = wc * (BN / 2) + ni * 16 + (lane & 15);
      red[g * BN + col] = pm;
    }
    __syncthreads();
    if (OUT == 4) {
      if (t < BN) {
        float m = red[t];
        #pragma unroll
        for (int g = 1; g < 8; ++g) m = fmaxf(m, red[g * BN + t]);
        Cf[(long)(z * mtiles + by) * ldC + n0 + t] = m;
      }
    } else {
      constexpr int NGR = BM / 64, PG = 8 / NGR;
      if (t < NGR * BN) {
        int hh = t / BN, col = t - hh * BN;
        float m = red[(hh * PG) * BN + col];
        #pragma unroll
        for (int i = 1; i < PG; ++i) m = fmaxf(m, red[(hh * PG + i) * BN + col]);
        Cf[(long)((m0 >> 6) + hh) * ldC + n0 + col] = m;
      }
    }
    return;
  }

  #pragma unroll
  for (int mi = 0; mi < MI; ++mi) {
    #pragma unroll
    for (int r = 0; r < 4; ++r) {
      int grow = m0 + wr * (BM / 2) + mi * 16 + (lane >> 4) * 4 + r;
      #pragma unroll
      for (int ni = 0; ni < NI; ++ni) {
        int gcol = n0 + wc * (BN / 2) + ni * 16 + (lane & 15);
        float v = acc[mi][ni][r];
        if (OUT == 1) {
          int b = grow >> 6, q = grow & 63;
          long dst = (long)b * 131072 + (long)((gcol >> 10) * 64 + q) * 1024 + (gcol & 1023);
          unsigned short h = f2bf(v);
          Ch[dst] = h;
          Cl[dst] = f2bf(v - bf2f(h));
        } else if (OUT == 2) {
          if (grow < M) Ch[(long)z * sC + (long)grow * ldC + gcol] = f2bf(v);
        } else if (OUT == 3) {
          long dst = (long)(grow >> 6) * 65536 + (long)gcol * 64 + (grow & 63);
          Ch[dst] = f2bf(v);
        }
      }
    }
  }
}

// ---------------- g1: Pcat || P3T (XCD-chunked swizzle, 1024 % 8 == 0) ----------------

__global__ __launch_bounds__(256) void g1_kernel(
    const unsigned short* Q_hi, const unsigned short* Q_lo,
    const unsigned short* Wcat_hi, const unsigned short* Wcat_lo,
    const unsigned short* W21T,
    unsigned short* Pcat_hi, unsigned short* Pcat_lo, unsigned short* P3T)
{
  __shared__ char smem[49152];
  int bid = (blockIdx.x & 7) * 128 + (blockIdx.x >> 3);
  if (bid < 512) {   // Pcat: M=2048,N=2048,K=1024, tile 128x64, split
    gemm_body<128, 64, true, 1, false>(smem, bid & 31, bid >> 5, 0,
        Q_hi, Q_lo, Wcat_hi, Wcat_lo, nullptr, nullptr, Pcat_hi, Pcat_lo,
        2048, 2048, 1024, 1024, 1024, 0, 0, 0, 0, 0);
  } else {           // P3T: M=2048,N=1024,K=1024, tile 64x64
    int b2 = bid - 512;
    gemm_body<64, 64, false, 3, false>(smem, b2 & 15, b2 >> 4, 0,
        Q_hi, nullptr, W21T, nullptr, nullptr, nullptr, P3T, nullptr,
        2048, 1024, 1024, 1024, 1024, 0, 0, 0, 0, 0);
  }
}

// ---------------- g2: scores, tile 64x128, 8 waves, dbuf + reg-staged A ----------------

__global__ __launch_bounds__(512) void g2_kernel(
    const float* __restrict__ Afeat,
    const unsigned short* __restrict__ Pcat_hi, const unsigned short* __restrict__ Pcat_lo,
    unsigned short* __restrict__ aq, float* __restrict__ Spack2)
{
  __shared__ char smem[49152];  // 2 x (Ash 4K | Asl 4K | Bs 8K | Bsl 8K)
  int orig = blockIdx.x;
  int xcd = orig & 7, idx = orig >> 3;
  int z  = xcd * 4 + (idx >> 3);   // 4 batches per XCD -> Pcat L2-resident
  int by = idx & 7;
  const int m0 = by * 64;
  const int t = threadIdx.x, lane = t & 63;
  const int wid = t >> 6, wr = wid >> 1, wc = wid & 1;

  const float* Ab = Afeat + (long)z * 524288;
  const unsigned short* Bbh = Pcat_hi + (long)z * 131072;
  const unsigned short* Bbl = Pcat_lo + (long)z * 131072;

  auto Ash = [&](int c) { return smem + c * 24576; };
  auto Asl = [&](int c) { return smem + c * 24576 + 4096; };
  auto Bs  = [&](int c) { return smem + c * 24576 + 8192; };
  auto Bsl = [&](int c) { return smem + c * 24576 + 16384; };

  f32x4 acc[4];
  #pragma unroll
  for (int i = 0; i < 4; ++i) acc[i] = f32x4{0.f, 0.f, 0.f, 0.f};

  float4 va;
  auto loadA = [&](int k0) {
    int ob = t * 8;
    int e  = ob ^ (((ob >> 7) & 3) << 4);
    int m  = e >> 6, ke = (e & 63) >> 1;
    va = *(const float4*)(Ab + (long)(m0 + m) * 1024 + k0 + ke);
  };
  auto writeA = [&](int c) {
    int ob = t * 8;
    ushort4 h, l;
    h.x = f2bf(va.x); l.x = f2bf(va.x - bf2f(h.x));
    h.y = f2bf(va.y); l.y = f2bf(va.y - bf2f(h.y));
    h.z = f2bf(va.z); l.z = f2bf(va.z - bf2f(h.z));
    h.w = f2bf(va.w); l.w = f2bf(va.w - bf2f(h.w));
    *(ushort4*)(Ash(c) + ob) = h;
    *(ushort4*)(Asl(c) + ob) = l;
  };
  auto stageB = [&](int c, int k0) {
    int ob = t * 16;
    int e  = ob ^ (((ob >> 7) & 3) << 4);
    int n  = e >> 6, kk = (e & 63) >> 1;
    const unsigned short* gp  = Bbh + (long)n * 1024 + k0 + kk;
    const unsigned short* gpl = Bbl + (long)n * 1024 + k0 + kk;
    char* lp  = Bs(c)  + (t & ~63) * 16;
    char* lpl = Bsl(c) + (t & ~63) * 16;
    __builtin_amdgcn_global_load_lds((gas_t)(const void*)gp,  (las_t)(void*)lp,  16, 0, 0);
    __builtin_amdgcn_global_load_lds((gas_t)(const void*)gpl, (las_t)(void*)lpl, 16, 0, 0);
  };
  auto ldfrag = [&](const char* lbuf, int rr) -> bf16x8 {
    int ob = rr * 64 + (lane >> 4) * 16;
    ob ^= ((ob >> 7) & 3) << 4;
    return *(const bf16x8*)(lbuf + ob);
  };

  // prologue
  loadA(0);
  stageB(0, 0);
  writeA(0);
  __syncthreads();

  int cur = 0;
  for (int k0 = 0; k0 < 1024; k0 += 32) {
    bool more = (k0 + 32) < 1024;
    if (more) {
      loadA(k0 + 32);        // global->reg, latency hidden under compute
      stageB(cur ^ 1, k0 + 32);
    }
    bf16x8 ah  = ldfrag(Ash(cur), wr * 16 + (lane & 15));
    bf16x8 alo = ldfrag(Asl(cur), wr * 16 + (lane & 15));
    #pragma unroll
    for (int ni = 0; ni < 4; ++ni) {
      bf16x8 bh = ldfrag(Bs(cur),  wc * 64 + ni * 16 + (lane & 15));
      bf16x8 bl = ldfrag(Bsl(cur), wc * 64 + ni * 16 + (lane & 15));
      acc[ni] = __builtin_amdgcn_mfma_f32_16x16x32_bf16(ah,  bh, acc[ni], 0, 0, 0);
      acc[ni] = __builtin_amdgcn_mfma_f32_16x16x32_bf16(ah,  bl, acc[ni], 0, 0, 0);
      acc[ni] = __builtin_amdgcn_mfma_f32_16x16x32_bf16(alo, bh, acc[ni], 0, 0, 0);
    }
    if (more) writeA(cur ^ 1);
    __syncthreads();
    cur ^= 1;
  }

  // epilogue: wc=0 waves hold aq scores (cols 0..63) -> fused row softmax;
  // wc=1 waves hold qa scores (cols 64..127) -> Spack2 fp32.
  #pragma unroll
  for (int r = 0; r < 4; ++r) {
    int grow = m0 + wr * 16 + (lane >> 4) * 4 + r;
    long base = (long)z * 32768 + (long)grow * 64 + (lane & 15);
    float v0 = acc[0][r], v1 = acc[1][r], v2 = acc[2][r], v3 = acc[3][r];
    if (wc == 0) {
      float mx = fmaxf(fmaxf(v0, v1), fmaxf(v2, v3));
      #pragma unroll
      for (int off = 8; off; off >>= 1) mx = fmaxf(mx, __shfl_xor(mx, off));
      float e0 = __expf(v0 - mx), e1 = __expf(v1 - mx);
      float e2 = __expf(v2 - mx), e3 = __expf(v3 - mx);
      float s = (e0 + e1) + (e2 + e3);
      #pragma unroll
      for (int off = 8; off; off >>= 1) s += __shfl_xor(s, off);
      float inv = 1.0f / s;
      aq[base]      = f2bf(e0 * inv);
      aq[base + 16] = f2bf(e1 * inv);
      aq[base + 32] = f2bf(e2 * inv);
      aq[base + 48] = f2bf(e3 * inv);
    } else {
      Spack2[base]      = v0;
      Spack2[base + 16] = v1;
      Spack2[base + 32] = v2;
      Spack2[base + 48] = v3;
    }
  }
}

// ---------------- qa col-softmax ----------------

__global__ __launch_bounds__(256) void softmax_cols(const float* __restrict__ S2,
                                                    unsigned short* __restrict__ qa)
{
  int bq = blockIdx.x;
  int b = bq >> 6, q = bq & 63;
  int t = threadIdx.x;
  const float* base = S2 + (long)b * 32768 + q;
  float v0 = base[(long)t * 64];
  float v1 = base[(long)(t + 256) * 64];
  float m = fmaxf(v0, v1);
  #pragma unroll
  for (int off = 32; off; off >>= 1) m = fmaxf(m, __shfl_xor(m, off));
  __shared__ float sm[4], ss[4];
  int wid = t >> 6, lane = t & 63;
  if (lane == 0) sm[wid] = m;
  __syncthreads();
  float M = fmaxf(fmaxf(sm[0], sm[1]), fmaxf(sm[2], sm[3]));
  float e0 = __expf(v0 - M), e1 = __expf(v1 - M);
  float s = e0 + e1;
  #pragma unroll
  for (int off = 32; off; off >>= 1) s += __shfl_xor(s, off);
  if (lane == 0) ss[wid] = s;
  __syncthreads();
  float inv = 1.0f / ((ss[0] + ss[1]) + (ss[2] + ss[3]));
  qa[(long)bq * 512 + t]       = f2bf(e0 * inv);
  qa[(long)bq * 512 + t + 256] = f2bf(e1 * inv);
}

// ---------------- g3: PmaxA || ctx (1536 % 8 == 0 -> chunked swizzle) ----------------

__global__ __launch_bounds__(256) void g3_kernel(
    const unsigned short* aq, const unsigned short* P3T, float* PmaxA,
    const unsigned short* qa, const float* Afeat, unsigned short* ctx)
{
  __shared__ char smem[32768];
  int bid = (blockIdx.x & 7) * 192 + (blockIdx.x >> 3);
  if (bid < 1024) {  // PmaxA: per batch M=512,N=1024,K=64, tile 128x128
    gemm_body<128, 128, false, 4, false>(smem, bid & 7, (bid >> 3) & 3, bid >> 5,
        aq, nullptr, P3T, nullptr, nullptr, PmaxA, nullptr, nullptr,
        512, 1024, 64, 64, 64, 1024, 32768L, 65536L, 0, 4);
  } else {           // ctx: per batch M=64,N=1024,K=512, tile 64x64, B = A fp32 (k-major)
    int b2 = bid - 1024;
    gemm_body<64, 64, false, 2, true>(smem, b2 & 15, 0, b2 >> 4,
        qa, nullptr, nullptr, nullptr, Afeat, nullptr, ctx, nullptr,
        64, 1024, 512, 512, 1024, 1024, 32768L, 524288L, 65536L, 0);
  }
}

// ---------------- g4 + final ----------------

__global__ __launch_bounds__(256) void g4_kernel(
    const unsigned short* ctx, const unsigned short* W22T, float* PmaxQ)
{
  __shared__ char smem[16384];
  gemm_body<64, 64, false, 5, false>(smem, blockIdx.x, blockIdx.y, 0,
      ctx, nullptr, W22T, nullptr, nullptr, PmaxQ, nullptr, nullptr,
      2048, 1024, 1024, 1024, 1024, 1024, 0, 0, 0, 0);
}

__global__ __launch_bounds__(256) void final_combine(
    const float* __restrict__ PmaxA, const float* __restrict__ PmaxQ, float* __restrict__ out)
{
  int idx = blockIdx.x * 256 + threadIdx.x;  // 32768
  int b = idx >> 10, h = idx & 1023;
  float m = PmaxA[(long)(b * 4) * 1024 + h];
  #pragma unroll
  for (int mt = 1; mt < 4; ++mt)
    m = fmaxf(m, PmaxA[(long)(b * 4 + mt) * 1024 + h]);
  out[idx] = 0.5f * m + 0.5f * PmaxQ[idx];
}

// ---------------- launch ----------------

extern "C" void kernel_launch(void* const* d_in, const int* in_sizes, int n_in,
                              void* d_out, int out_size, void* d_ws, size_t ws_size,
                              hipStream_t stream) {
  const float* Afeat = (const float*)d_in[0];
  const float* Qfeat = (const float*)d_in[1];
  const float* W11   = (const float*)d_in[2];
  const float* W12   = (const float*)d_in[3];
  const float* W21   = (const float*)d_in[4];
  const float* W22   = (const float*)d_in[5];
  float* out = (float*)d_out;

  char* w = (char*)d_ws;
  auto alloc = [&](long bytes) { char* p = w; w += bytes; return p; };
  unsigned short* Q_hi    = (unsigned short*)alloc(4194304);
  unsigned short* Q_lo    = (unsigned short*)alloc(4194304);
  unsigned short* Wcat_hi = (unsigned short*)alloc(4194304);   // [2048][1024]
  unsigned short* Wcat_lo = (unsigned short*)alloc(4194304);
  unsigned short* W21T    = (unsigned short*)alloc(2097152);
  unsigned short* W22T    = (unsigned short*)alloc(2097152);
  unsigned short* Pcat_hi = (unsigned short*)alloc(8388608);   // [32][128][1024]
  unsigned short* Pcat_lo = (unsigned short*)alloc(8388608);
  unsigned short* P3T     = (unsigned short*)alloc(4194304);   // [32][1024][64]
  float*          Spack2  = (float*)alloc(4194304);            // [32][512][64]
  unsigned short* aq      = (unsigned short*)alloc(2097152);   // [32][512][64]
  unsigned short* qa      = (unsigned short*)alloc(2097152);   // [32][64][512]
  unsigned short* ctx     = (unsigned short*)alloc(4194304);   // [32][64][1024]
  float*          PmaxA   = (float*)alloc(524288);             // [128][1024]
  float*          PmaxQ   = (float*)alloc(131072);             // [32][1024]

  dim3 blk(256), tblk(32, 8);

  conv_split<<<2048, blk, 0, stream>>>(Qfeat, Q_hi, Q_lo, 524288);
  prep_W<<<dim3(32, 32, 4), tblk, 0, stream>>>(W11, W12, W21, W22, Wcat_hi, Wcat_lo, W21T, W22T);

  g1_kernel<<<1024, blk, 0, stream>>>(Q_hi, Q_lo, Wcat_hi, Wcat_lo, W21T, Pcat_hi, Pcat_lo, P3T);
  g2_kernel<<<256, dim3(512), 0, stream>>>(Afeat, Pcat_hi, Pcat_lo, aq, Spack2);
  softmax_cols<<<2048, blk, 0, stream>>>(Spack2, qa);
  g3_kernel<<<1536, blk, 0, stream>>>(aq, P3T, PmaxA, qa, Afeat, ctx);
  g4_kernel<<<dim3(16, 32), blk, 0, stream>>>(ctx, W22T, PmaxQ);
  final_combine<<<128, blk, 0, stream>>>(PmaxA, PmaxQ, out);
}